// Round 2
// baseline (799.256 us; speedup 1.0000x reference)
//
#include <hip/hip_runtime.h>
#include <hip/hip_bf16.h>

typedef short short8 __attribute__((ext_vector_type(8)));
typedef float f32x4 __attribute__((ext_vector_type(4)));

#define NPTS 4096
#define BATCH 8
#define PTOT (BATCH*NPTS)      // 32768
#define FEATS 128
#define KK 20
#define OUTC 64
#define PTS_PER_WAVE 8
#define WAVES 4

__device__ __forceinline__ unsigned short f2bf(float f){
  union { __hip_bfloat16 h; unsigned short u; } v;
  v.h = __hip_bfloat16(f);
  return v.u;
}

// feature [B,128,N] f32  ->  flat [B*N, 128] bf16
__global__ void k_transpose(const float* __restrict__ f, unsigned short* __restrict__ flat){
  __shared__ float tile[32][33];
  int b = blockIdx.z, c0 = blockIdx.y*32, n0 = blockIdx.x*32;
  int tx = threadIdx.x, ty = threadIdx.y;   // (32,8)
  const float* src = f + ((size_t)b*FEATS + c0)*NPTS + n0;
  #pragma unroll
  for(int i=0;i<4;i++) tile[ty+8*i][tx] = src[(size_t)(ty+8*i)*NPTS + tx];
  __syncthreads();
  unsigned short* dst = flat + ((size_t)b*NPTS + n0)*FEATS + c0;
  #pragma unroll
  for(int i=0;i<4;i++) dst[(size_t)(ty+8*i)*FEATS + tx] = f2bf(tile[tx][ty+8*i]);
}

// perm fragment loads: praw[nt*8+j] = perm[p][k=lg*8+j][s=nt*16+l15] (addr-clamped)
#define LOAD_PERM(P, DST) do {                                   \
    const float* pb_ = perm_g + (size_t)(P)*400;                 \
    _Pragma("unroll")                                            \
    for(int nt_=0; nt_<2; nt_++){                                \
      int s_ = nt_*16 + l15; if(s_>=KK) s_ = 0;                  \
      _Pragma("unroll")                                          \
      for(int j_=0;j_<8;j_++){                                   \
        int k_ = lg*8+j_; if(k_>=KK) k_ = 0;                     \
        (DST)[nt_*8+j_] = pb_[k_*20 + s_];                       \
      }                                                          \
    }                                                            \
  } while(0)

__global__ __launch_bounds__(256, 3) void k_main(
    const unsigned short* __restrict__ flat,
    const float* __restrict__ perm_g,
    const float* __restrict__ convw,
    const int*   __restrict__ idx_g,
    float* __restrict__ out,
    float* __restrict__ stats)
{
  const int t    = threadIdx.x;
  const int lane = t & 63;
  const int w    = t >> 6;      // wave 0..3, one point-stream each
  const int l15  = lane & 15;
  const int lg   = lane >> 4;

  // W swizzled [o][c'] bf16 (shared, read-only after barrier); tmp per-wave private
  __shared__ __align__(16) unsigned short W_lds[OUTC*FEATS];          // 16 KB
  __shared__ __align__(16) unsigned short tmp_all[WAVES][KK*FEATS];   // 4 x 5 KB

  // ---- stage W once: f32 -> bf16, XOR-swizzled rows ----
  for(int e=t; e<OUTC*FEATS; e+=256){
    int o = e >> 7, c = e & 127;
    int byt = (o*256 + c*2) ^ ((o&7)<<4);
    *(unsigned short*)((char*)W_lds + byt) = f2bf(convw[e]);
  }
  __syncthreads();   // the ONLY barrier

  unsigned short* tmp = tmp_all[w];
  const unsigned short* flatl = flat + l15;   // fold lane column into base

  float bs[16], bq[16];
  #pragma unroll
  for(int i=0;i<16;i++){ bs[i]=0.f; bq[i]=0.f; }

  const int p0 = blockIdx.x*(WAVES*PTS_PER_WAVE) + w*PTS_PER_WAVE;
  const int lane_sw_base = lg*160 + l15*2;    // 2*(lg*80 + l15)

  // prologue prefetch: idx + perm for first point
  int   idxv[2];
  float praw[2][16];
  idxv[0] = (lane < KK) ? idx_g[(size_t)p0*KK + lane] : 0;
  LOAD_PERM(p0, praw[0]);

  #pragma unroll
  for(int i=0; i<PTS_PER_WAVE; i++){
    const int p   = p0 + i;
    const int cur = i & 1, nxt = cur ^ 1;

    // ---- row pointers + issue all 64 A-loads (oldest in vmcnt queue) ----
    const unsigned short* rp[8];
    #pragma unroll
    for(int j=0;j<8;j++){
      int k = lg*8 + j;
      int sk = __shfl(idxv[cur], (k<KK)? k : (KK-1));
      rp[j] = flatl + (size_t)sk*FEATS;
    }
    unsigned short au[8][8];
    #pragma unroll
    for(int mt=0; mt<8; mt++)
      #pragma unroll
      for(int j=0; j<8; j++)
        au[mt][j] = rp[j][mt*16];

    // ---- build B-fragments from last iteration's perm prefetch (VALU only) ----
    short8 bfr[2];
    #pragma unroll
    for(int nt=0; nt<2; nt++)
      #pragma unroll
      for(int j=0; j<8; j++)
        bfr[nt][j] = (short)f2bf(praw[cur][nt*8+j]);

    // ---- prefetch next point's idx + perm (younger than A-loads) ----
    if(i+1 < PTS_PER_WAVE){
      idxv[nxt] = (lane < KK) ? idx_g[(size_t)(p+1)*KK + lane] : 0;
      LOAD_PERM(p+1, praw[nxt]);
    }

    // ---- GEMM1: tmp[c][s] = sum_k A[c][k]*perm[k][s], stored in .view layout ----
    #pragma unroll
    for(int mt=0; mt<8; mt++){
      short8 af;
      #pragma unroll
      for(int j=0; j<8; j++){
        int k = lg*8 + j;
        af[j] = (k<KK) ? (short)au[mt][j] : (short)0;   // zero pad-K
      }
      f32x4 z = {0.f,0.f,0.f,0.f};
      f32x4 a0 = __builtin_amdgcn_mfma_f32_16x16x32_bf16(af, bfr[0], z, 0,0,0);
      f32x4 a1 = __builtin_amdgcn_mfma_f32_16x16x32_bf16(af, bfr[1], z, 0,0,0);
      // byte = 2*fidx ^ ((row&7)<<4), fidx = (mt*16+lg*4+r)*20 + s
      #pragma unroll
      for(int r=0; r<4; r++){
        int t0 = lane_sw_base + mt*640 + r*40;          // nt=0 (s = l15)
        int b0 = t0 ^ (((t0>>8)&7)<<4);
        *(unsigned short*)((char*)tmp + b0) = f2bf(a0[r]);
        if(l15 < 4){                                     // nt=1 valid s = 16..19
          int t1 = t0 + 32;
          int b1 = t1 ^ (((t1>>8)&7)<<4);
          *(unsigned short*)((char*)tmp + b1) = f2bf(a1[r]);
        }
      }
    }

    // ---- GEMM2: Y[o][kp] = sum_c' W[o][c'] * tmp[kp][c']  (K=128) ----
    f32x4 acc2[4][2];
    #pragma unroll
    for(int m2=0;m2<4;m2++)
      #pragma unroll
      for(int nt=0;nt<2;nt++){ f32x4 z={0.f,0.f,0.f,0.f}; acc2[m2][nt]=z; }

    #pragma unroll
    for(int ks=0; ks<4; ks++){
      short8 bf[2];
      #pragma unroll
      for(int nt=0; nt<2; nt++){
        int kp  = nt*16 + l15;
        int row = (kp < KK) ? kp : l15;                  // clamp pad rows (<20, masked later)
        int byt = (row*256 + ks*64 + lg*16) ^ ((row&7)<<4);
        bf[nt] = *(const short8*)((const char*)tmp + byt);
      }
      #pragma unroll
      for(int m2=0; m2<4; m2++){
        int o  = m2*16 + l15;
        int wb = (o*256 + ks*64 + lg*16) ^ ((o&7)<<4);
        short8 wf = *(const short8*)((const char*)W_lds + wb);
        acc2[m2][0] = __builtin_amdgcn_mfma_f32_16x16x32_bf16(wf, bf[0], acc2[m2][0], 0,0,0);
        acc2[m2][1] = __builtin_amdgcn_mfma_f32_16x16x32_bf16(wf, bf[1], acc2[m2][1], 0,0,0);
      }
    }

    // ---- epilogue: max over kp (bias cancels under BN), store, BN partials ----
    #pragma unroll
    for(int m2=0; m2<4; m2++){
      #pragma unroll
      for(int r=0; r<4; r++){
        float m  = acc2[m2][0][r];
        float v1 = (l15 < 4) ? acc2[m2][1][r] : -3.4e38f;
        m = fmaxf(m, v1);
        #pragma unroll
        for(int off=1; off<16; off<<=1) m = fmaxf(m, __shfl_xor(m, off));
        if(l15 == 0){
          int o = m2*16 + lg*4 + r;
          int bb = p >> 12, nn = p & (NPTS-1);
          out[((size_t)bb*OUTC + o)*NPTS + nn] = m;
          bs[m2*4+r] += m; bq[m2*4+r] += m*m;
        }
      }
    }
  }

  if(l15 == 0){
    #pragma unroll
    for(int m2=0; m2<4; m2++)
      #pragma unroll
      for(int r=0; r<4; r++){
        int o = m2*16 + lg*4 + r;
        atomicAdd(&stats[o],    bs[m2*4+r]);
        atomicAdd(&stats[64+o], bq[m2*4+r]);
      }
  }
}

__global__ void k_finalize(const float* __restrict__ stats,
                           const float* __restrict__ gamma,
                           const float* __restrict__ beta,
                           float* __restrict__ ss){
  int o = threadIdx.x;   // 64
  float inv = 1.f/(float)PTOT;
  float mean = stats[o]*inv;
  float var  = stats[64+o]*inv - mean*mean;
  float rstd = rsqrtf(var + 1e-5f);
  float sc = gamma[o]*rstd;
  ss[o] = sc;
  ss[64+o] = beta[o] - mean*sc;
}

__global__ void k_bn(float* __restrict__ out, const float* __restrict__ ss){
  int i = blockIdx.x*256 + threadIdx.x;     // over float4s
  float4 v = ((float4*)out)[i];
  int o = (i >> 10) & 63;
  float sc = ss[o], sh = ss[64+o];
  v.x = v.x*sc + sh; v.y = v.y*sc + sh; v.z = v.z*sc + sh; v.w = v.w*sc + sh;
  ((float4*)out)[i] = v;
}

extern "C" void kernel_launch(void* const* d_in, const int* in_sizes, int n_in,
                              void* d_out, int out_size, void* d_ws, size_t ws_size,
                              hipStream_t stream){
  (void)in_sizes; (void)n_in; (void)ws_size;
  const float* feature    = (const float*)d_in[0];
  const float* permatrix  = (const float*)d_in[1];
  const float* conv_w     = (const float*)d_in[2];
  // d_in[3] = conv_b: mathematically cancelled by training-mode BatchNorm
  const float* bn_gamma   = (const float*)d_in[4];
  const float* bn_beta    = (const float*)d_in[5];
  const int*   sp_idx     = (const int*)d_in[6];
  float* out = (float*)d_out;

  unsigned short* flat = (unsigned short*)d_ws;                       // 8 MB
  float* stats = (float*)((char*)d_ws + (size_t)8*1024*1024);         // 128 f32
  float* ss    = stats + 128;                                         // 128 f32

  hipMemsetAsync(stats, 0, 128*sizeof(float), stream);

  dim3 gT(NPTS/32, FEATS/32, BATCH), bT(32,8);
  k_transpose<<<gT, bT, 0, stream>>>(feature, flat);

  k_main<<<dim3(PTOT/(WAVES*PTS_PER_WAVE)), dim3(256), 0, stream>>>(
      flat, permatrix, conv_w, sp_idx, out, stats);

  k_finalize<<<dim3(1), dim3(64), 0, stream>>>(stats, bn_gamma, bn_beta, ss);

  k_bn<<<dim3(out_size/4/256), dim3(256), 0, stream>>>(out, ss);
}

// Round 3
// 185.131 us; speedup vs baseline: 4.3173x; 4.3173x over previous
//
#include <hip/hip_runtime.h>
#include <hip/hip_bf16.h>

typedef short short8 __attribute__((ext_vector_type(8)));
typedef float f32x4 __attribute__((ext_vector_type(4)));
typedef unsigned int uint2v __attribute__((ext_vector_type(2)));

#define NPTS 4096
#define BATCH 8
#define PTOT (BATCH*NPTS)      // 32768
#define FEATS 128
#define KK 20
#define OUTC 64
#define PTS_PER_WAVE 8
#define WAVES 4

__device__ __forceinline__ unsigned short f2bf(float f){
  union { __hip_bfloat16 h; unsigned short u; } v;
  v.h = __hip_bfloat16(f);
  return v.u;
}

// feature [B,128,N] f32  ->  flat [B*N, 128] bf16
__global__ void k_transpose(const float* __restrict__ f, unsigned short* __restrict__ flat){
  __shared__ float tile[32][33];
  int b = blockIdx.z, c0 = blockIdx.y*32, n0 = blockIdx.x*32;
  int tx = threadIdx.x, ty = threadIdx.y;   // (32,8)
  const float* src = f + ((size_t)b*FEATS + c0)*NPTS + n0;
  #pragma unroll
  for(int i=0;i<4;i++) tile[ty+8*i][tx] = src[(size_t)(ty+8*i)*NPTS + tx];
  __syncthreads();
  unsigned short* dst = flat + ((size_t)b*NPTS + n0)*FEATS + c0;
  #pragma unroll
  for(int i=0;i<4;i++) dst[(size_t)(ty+8*i)*FEATS + tx] = f2bf(tile[tx][ty+8*i]);
}

__global__ __launch_bounds__(256, 4) void k_main(
    const unsigned short* __restrict__ flat,
    const float* __restrict__ perm_g,
    const float* __restrict__ convw,
    const int*   __restrict__ idx_g,
    float* __restrict__ out,
    float* __restrict__ stats)
{
  const int t    = threadIdx.x;
  const int lane = t & 63;
  const int w    = t >> 6;      // wave 0..3, one point-stream each
  const int l15  = lane & 15;
  const int lg   = lane >> 4;

  __shared__ __align__(16) unsigned short W_lds[OUTC*FEATS];          // 16 KB, [o][c'] swizzled
  __shared__ __align__(16) unsigned short tmp_all[WAVES][KK*FEATS];   // 4 x 5 KB, fidx-linear swizzled
  __shared__ float red[WAVES*2*OUTC];                                 // 2 KB stats partials

  // ---- stage W once: row-major [o][c'] bf16, XOR-swizzled ----
  for(int e=t; e<OUTC*FEATS; e+=256){
    int o = e >> 7, c = e & 127;
    int byt = (o*256 + c*2) ^ ((o&7)<<4);
    *(unsigned short*)((char*)W_lds + byt) = f2bf(convw[e]);
  }
  __syncthreads();

  unsigned short* tmp = tmp_all[w];

  // point-invariant per-lane constants
  const int s2 = (l15 < 4) ? (16 + l15) : 19;     // clamped second s-tile
  int koff[8];                                     // clamped k*20 offsets (in-bounds)
  #pragma unroll
  for(int j=0;j<8;j++){
    int kb = lg*160 + j*20;
    koff[j] = (kb > 380) ? 380 : kb;
  }

  float bsum[4] = {0.f,0.f,0.f,0.f};
  float bsq [4] = {0.f,0.f,0.f,0.f};

  for(int pi=0; pi<PTS_PER_WAVE; pi++){
    const int p  = blockIdx.x*(WAVES*PTS_PER_WAVE) + w*PTS_PER_WAVE + pi;
    const int pb = __builtin_amdgcn_readfirstlane(p);

    // ---- spiral indices: lane k holds idx[k] ----
    int skv = idx_g[(size_t)pb*KK + ((lane < KK) ? lane : (KK-1))];

    // ---- perm A-operand loads (clamped addresses; zeroed below for k>=20) ----
    const float* permb = perm_g + (size_t)pb*400;
    float p0r[8], p1r[8];
    #pragma unroll
    for(int j=0;j<8;j++){
      p0r[j] = permb[koff[j] + l15];   // s = l15
      p1r[j] = permb[koff[j] + s2];    // s = 16+l15 (clamped)
    }

    // ---- per-lane gather row base pointers (k = lg*8+j, clamped) ----
    const unsigned short* vb[8];
    #pragma unroll
    for(int j=0;j<8;j++){
      int kk = lg*8 + j; if(kk >= KK) kk = KK-1;
      int sk = __shfl(skv, kk);
      vb[j] = flat + (size_t)sk*FEATS + l15;
    }

    // ---- perm -> bf16 A-frags, zero k>=20 (keeps 0 * finite = 0) ----
    short8 a0f, a1f;
    #pragma unroll
    for(int j=0;j<8;j++){
      int kk = lg*8 + j;
      a0f[j] = (kk < KK) ? (short)f2bf(p0r[j]) : (short)0;
      a1f[j] = (kk < KK) ? (short)f2bf(p1r[j]) : (short)0;
    }

    // ---- GEMM1 (swapped): D[s][c] = sum_k perm[k][s] * gathered[k][c] ----
    #pragma unroll
    for(int nt=0; nt<8; nt++){
      short8 gf;
      #pragma unroll
      for(int j=0;j<8;j++) gf[j] = (short)vb[j][nt*16];   // c = nt*16 + l15
      f32x4 z = {0.f,0.f,0.f,0.f};
      f32x4 c0 = __builtin_amdgcn_mfma_f32_16x16x32_bf16(a0f, gf, z, 0,0,0);
      f32x4 c1 = __builtin_amdgcn_mfma_f32_16x16x32_bf16(a1f, gf, z, 0,0,0);
      const int c = nt*16 + l15;
      {
        // s = 4*lg + r : fidx = c*20 + 4lg + r -> 4 consecutive -> one b64
        int f0  = c*20 + lg*4;
        int byt = (f0*2) ^ (((f0>>7)&7)<<4);
        uint2v pk;
        pk.x = (unsigned)f2bf(c0[0]) | ((unsigned)f2bf(c0[1])<<16);
        pk.y = (unsigned)f2bf(c0[2]) | ((unsigned)f2bf(c0[3])<<16);
        *(uint2v*)((char*)tmp + byt) = pk;
      }
      if(lg == 0){
        // s = 16 + r
        int f0  = c*20 + 16;
        int byt = (f0*2) ^ (((f0>>7)&7)<<4);
        uint2v pk;
        pk.x = (unsigned)f2bf(c1[0]) | ((unsigned)f2bf(c1[1])<<16);
        pk.y = (unsigned)f2bf(c1[2]) | ((unsigned)f2bf(c1[3])<<16);
        *(uint2v*)((char*)tmp + byt) = pk;
      }
    }

    // ---- GEMM2 (swapped): D[kp][o] = sum_c' T[kp][c'] * W[o][c'] ----
    f32x4 acc[2][4];
    #pragma unroll
    for(int m2=0;m2<2;m2++)
      #pragma unroll
      for(int n2=0;n2<4;n2++){ f32x4 z={0.f,0.f,0.f,0.f}; acc[m2][n2]=z; }

    const int kp0 = l15;
    const int kp1 = (l15 < 4) ? (16 + l15) : 19;   // clamped; duplicates masked in epilogue
    #pragma unroll
    for(int ks=0; ks<4; ks++){
      int a0b = (kp0*256 + ks*64 + lg*16) ^ ((kp0&7)<<4);
      int a1b = (kp1*256 + ks*64 + lg*16) ^ ((kp1&7)<<4);
      short8 t0 = *(const short8*)((const char*)tmp + a0b);
      short8 t1 = *(const short8*)((const char*)tmp + a1b);
      #pragma unroll
      for(int n2=0; n2<4; n2++){
        int o  = n2*16 + l15;
        int wb = (o*256 + ks*64 + lg*16) ^ ((o&7)<<4);
        short8 wf = *(const short8*)((const char*)W_lds + wb);
        acc[0][n2] = __builtin_amdgcn_mfma_f32_16x16x32_bf16(t0, wf, acc[0][n2], 0,0,0);
        acc[1][n2] = __builtin_amdgcn_mfma_f32_16x16x32_bf16(t1, wf, acc[1][n2], 0,0,0);
      }
    }

    // ---- epilogue: max over kp (3 fmax + mask + 2 shfl), store, stats ----
    const int bb = p >> 12, nn = p & (NPTS-1);
    #pragma unroll
    for(int n2=0; n2<4; n2++){
      float m0 = fmaxf(fmaxf(acc[0][n2][0], acc[0][n2][1]),
                       fmaxf(acc[0][n2][2], acc[0][n2][3]));
      float m1 = fmaxf(fmaxf(acc[1][n2][0], acc[1][n2][1]),
                       fmaxf(acc[1][n2][2], acc[1][n2][3]));
      float mm = fmaxf(m0, (lg == 0) ? m1 : -3.4e38f);
      mm = fmaxf(mm, __shfl_xor(mm, 16));
      mm = fmaxf(mm, __shfl_xor(mm, 32));
      if(lg == 0){
        int o = n2*16 + l15;
        out[((size_t)bb*OUTC + o)*NPTS + nn] = mm;   // conv bias cancels under train-mode BN
      }
      bsum[n2] += mm; bsq[n2] += mm*mm;
    }
  }

  // ---- block-level stats reduction -> 2 atomics per channel per block ----
  __syncthreads();
  if(lg == 0){
    #pragma unroll
    for(int n2=0; n2<4; n2++){
      int o = n2*16 + l15;
      red[w*128 + o]      = bsum[n2];
      red[w*128 + 64 + o] = bsq[n2];
    }
  }
  __syncthreads();
  if(w == 0){
    float s0 = red[lane] + red[128+lane] + red[256+lane] + red[384+lane];
    atomicAdd(&stats[lane], s0);
  } else if(w == 1){
    float s1 = red[64+lane] + red[192+lane] + red[320+lane] + red[448+lane];
    atomicAdd(&stats[64+lane], s1);
  }
}

__global__ void k_finalize(const float* __restrict__ stats,
                           const float* __restrict__ gamma,
                           const float* __restrict__ beta,
                           float* __restrict__ ss){
  int o = threadIdx.x;   // 64
  float inv = 1.f/(float)PTOT;
  float mean = stats[o]*inv;
  float var  = stats[64+o]*inv - mean*mean;
  float rstd = rsqrtf(var + 1e-5f);
  float sc = gamma[o]*rstd;
  ss[o] = sc;
  ss[64+o] = beta[o] - mean*sc;
}

__global__ void k_bn(float* __restrict__ out, const float* __restrict__ ss){
  int i = blockIdx.x*256 + threadIdx.x;     // over float4s
  float4 v = ((float4*)out)[i];
  int o = (i >> 10) & 63;
  float sc = ss[o], sh = ss[64+o];
  v.x = v.x*sc + sh; v.y = v.y*sc + sh; v.z = v.z*sc + sh; v.w = v.w*sc + sh;
  ((float4*)out)[i] = v;
}

extern "C" void kernel_launch(void* const* d_in, const int* in_sizes, int n_in,
                              void* d_out, int out_size, void* d_ws, size_t ws_size,
                              hipStream_t stream){
  (void)in_sizes; (void)n_in; (void)ws_size;
  const float* feature    = (const float*)d_in[0];
  const float* permatrix  = (const float*)d_in[1];
  const float* conv_w     = (const float*)d_in[2];
  // d_in[3] = conv_b: cancelled exactly by training-mode BatchNorm
  const float* bn_gamma   = (const float*)d_in[4];
  const float* bn_beta    = (const float*)d_in[5];
  const int*   sp_idx     = (const int*)d_in[6];
  float* out = (float*)d_out;

  unsigned short* flat = (unsigned short*)d_ws;                       // 8 MB
  float* stats = (float*)((char*)d_ws + (size_t)8*1024*1024);         // 128 f32
  float* ss    = stats + 128;                                         // 128 f32

  hipMemsetAsync(stats, 0, 128*sizeof(float), stream);

  dim3 gT(NPTS/32, FEATS/32, BATCH), bT(32,8);
  k_transpose<<<gT, bT, 0, stream>>>(feature, flat);

  k_main<<<dim3(PTOT/(WAVES*PTS_PER_WAVE)), dim3(256), 0, stream>>>(
      flat, permatrix, conv_w, sp_idx, out, stats);

  k_finalize<<<dim3(1), dim3(64), 0, stream>>>(stats, bn_gamma, bn_beta, ss);

  k_bn<<<dim3(out_size/4/256), dim3(256), 0, stream>>>(out, ss);
}

// Round 6
// 118.151 us; speedup vs baseline: 6.7647x; 1.5669x over previous
//
#include <hip/hip_runtime.h>
#include <hip/hip_bf16.h>

typedef short short8 __attribute__((ext_vector_type(8)));
typedef short short4v __attribute__((ext_vector_type(4)));
typedef float f32x4 __attribute__((ext_vector_type(4)));
typedef unsigned int uint2v __attribute__((ext_vector_type(2)));

#define NPTS 4096
#define BATCH 8
#define PTOT 32768
#define FEATS 128
#define KK 20
#define OUTC 64
#define PTS_PER_WAVE 8
#define WAVES 4

__device__ __forceinline__ unsigned short f2bf(float f){
  union { __hip_bfloat16 h; unsigned short u; } v;
  v.h = __hip_bfloat16(f);
  return v.u;
}

__device__ __forceinline__ void gload_lds16(const void* src, void* dst){
  __builtin_amdgcn_global_load_lds((const __attribute__((address_space(1))) void*)src,
                                   (__attribute__((address_space(3))) void*)dst, 16, 0, 0);
}

// feature [B,128,N] f32 -> flat [B*N, 128] bf16
__global__ void k_transpose(const float* __restrict__ f, unsigned short* __restrict__ flat){
  __shared__ float tile[32][33];
  int b = blockIdx.z, c0 = blockIdx.y*32, n0 = blockIdx.x*32;
  int tx = threadIdx.x, ty = threadIdx.y;   // (32,8)
  const float* src = f + ((size_t)b*FEATS + c0)*NPTS + n0;
  #pragma unroll
  for(int i=0;i<4;i++) tile[ty+8*i][tx] = src[(size_t)(ty+8*i)*NPTS + tx];
  __syncthreads();
  unsigned short* dst = flat + ((size_t)b*NPTS + n0)*FEATS + c0;
  #pragma unroll
  for(int i=0;i<4;i++) dst[(size_t)(ty+8*i)*FEATS + tx] = f2bf(tile[tx][ty+8*i]);
}

// conv_w f32 [64][128] -> bf16 fragment table: e = (((ks*4+n2)*4+lg)*16+l15)*8+j
__global__ void k_wpack(const float* __restrict__ convw, unsigned short* __restrict__ wp){
  int e = blockIdx.x*256 + threadIdx.x;    // 8192 total
  int j = e & 7, l15 = (e>>3)&15, lg = (e>>7)&3, n2 = (e>>9)&3, ks = e>>11;
  int o = n2*16 + l15, c = ks*32 + lg*8 + j;
  wp[e] = f2bf(convw[o*FEATS + c]);
}

__global__ __launch_bounds__(256, 3) void k_main(
    const unsigned short* __restrict__ flat,
    const float* __restrict__ perm_g,
    const unsigned short* __restrict__ wpack,
    const int*   __restrict__ idx_g,
    float* __restrict__ out,
    float* __restrict__ stats)
{
  const int t = threadIdx.x, lane = t & 63, w = t >> 6;
  const int l15 = lane & 15, lg = lane >> 4;

  // gbuf = gather subtiles [cgrp 0..7][kgrp 0..4][4][16] u16 (DMA target)
  // tbuf = GEMM1 output in .view layout (fidx-linear, XOR-swizzled)
  __shared__ __align__(16) unsigned short gbuf_all[WAVES][2560];     // 5 KB/wave
  __shared__ __align__(16) unsigned short tbuf_all[WAVES][2560];     // 5 KB/wave
  __shared__ int   idx_all[WAVES][160];                              // 640 B/wave
  __shared__ float ybuf_all[WAVES][PTS_PER_WAVE*OUTC];               // 2 KB/wave
  __shared__ float red[WAVES*2*OUTC];                                // 2 KB

  unsigned short* gbuf = gbuf_all[w];
  unsigned short* tbuf = tbuf_all[w];
  int*   idxb = idx_all[w];
  float* ybuf = ybuf_all[w];
  const unsigned gbufb = (unsigned)(size_t)(const __attribute__((address_space(3))) void*)gbuf;

  const int p0 = blockIdx.x*(WAVES*PTS_PER_WAVE) + w*PTS_PER_WAVE;

  // ---- idx prefetch: 160 ints for this wave's 8 points (coalesced) ----
  {
    const int* ib = idx_g + (size_t)p0*KK;
    idxb[lane]      = ib[lane];
    idxb[64+lane]   = ib[64+lane];
    if(lane < 32) idxb[128+lane] = ib[128+lane];
  }

  // ---- per-lane staging map: chunk q = it*64+lane -> (cgrp,kgrp,krem,chalf) ----
  int krowb4[5], colb[5];
  #pragma unroll
  for(int it=0; it<5; it++){
    int q = it*64 + lane;
    int cg = q/40, r = q - cg*40;
    int kgr = r>>3, rem = r&7, krem = rem>>1, chalf = rem&1;
    krowb4[it] = (kgr*4 + krem)*4;      // idx byte offset for row k
    colb[it]   = cg*32 + chalf*16;      // byte offset within flat row
  }

  // ---- tr-read addresses: CROSS-LANE group-transpose semantics ----
  // Each 16-lane group collectively reads one [4][16] subtile in lane order
  // (lane i reads 8B at subtile_base + i*8); HW returns column i to lane i.
  int kg0 = 2*lg;   if(kg0 > 4) kg0 = 0;
  int kg1 = 2*lg+1; if(kg1 > 4) kg1 = 0;
  const unsigned tra0 = gbufb + kg0*128 + l15*8;
  const unsigned tra1 = gbufb + kg1*128 + l15*8;

  // ---- perm offsets (clamped in-bounds; A zeroed for k>=20) ----
  const int s2 = (l15 < 4) ? (16 + l15) : 19;
  int koff[8];
  #pragma unroll
  for(int j=0;j<8;j++){ int kb = lg*160 + j*20; koff[j] = (kb > 380) ? 380 : kb; }

  float bsum[4] = {0,0,0,0}, bsq[4] = {0,0,0,0};
  float p0r[8], p1r[8];

  #define STAGE(PI) do{                                                         \
    int pib_ = (PI)*80;                                                         \
    _Pragma("unroll")                                                           \
    for(int it_=0; it_<5; it_++){                                               \
      int id_ = *(const int*)((const char*)idxb + pib_ + krowb4[it_]);          \
      const char* s_ = (const char*)flat + ((size_t)(unsigned)id_*256) + colb[it_]; \
      gload_lds16(s_, (char*)gbuf + it_*1024);                                  \
    } }while(0)

  #define PERM(PI) do{                                                          \
    const float* pb_ = perm_g + (size_t)(p0+(PI))*400;                          \
    _Pragma("unroll")                                                           \
    for(int j_=0;j_<8;j_++){ p0r[j_] = pb_[koff[j_]+l15]; p1r[j_] = pb_[koff[j_]+s2]; } \
    }while(0)

  STAGE(0); PERM(0);

  for(int pi=0; pi<PTS_PER_WAVE; pi++){
    // ---- pack perm A-frags (compiler inserts vmcnt for p0r/p1r) ----
    short8 a0f, a1f;
    #pragma unroll
    for(int j=0;j<8;j++){
      int kk2 = lg*8 + j;
      a0f[j] = (kk2 < KK) ? (short)f2bf(p0r[j]) : (short)0;
      a1f[j] = (kk2 < KK) ? (short)f2bf(p1r[j]) : (short)0;
    }
    asm volatile("s_waitcnt vmcnt(0)" ::: "memory");   // staging DMA landed in gbuf

    // ---- 16 transpose-reads from gbuf: B-frag halves, reg-delivered ----
    short4v lo[8], hi[8];
    #pragma unroll
    for(int nt=0; nt<8; nt++){
      asm volatile("ds_read_b64_tr_b16 %0, %1 offset:%2" : "=v"(lo[nt]) : "v"(tra0), "i"(nt*640));
      asm volatile("ds_read_b64_tr_b16 %0, %1 offset:%2" : "=v"(hi[nt]) : "v"(tra1), "i"(nt*640));
    }
    asm volatile("s_waitcnt lgkmcnt(0)" ::: "memory");
    __builtin_amdgcn_sched_barrier(0);                 // rule #18: pin MFMAs after the wait

    // ---- GEMM1: D[s][c] = sum_k perm[k][s]*gath[k][c]; write .view layout to tbuf ----
    #pragma unroll
    for(int nt=0; nt<8; nt++){
      short8 gf = __builtin_shufflevector(lo[nt], hi[nt], 0,1,2,3,4,5,6,7);
      f32x4 z = {0.f,0.f,0.f,0.f};
      f32x4 c0 = __builtin_amdgcn_mfma_f32_16x16x32_bf16(a0f, gf, z, 0,0,0);
      f32x4 c1 = __builtin_amdgcn_mfma_f32_16x16x32_bf16(a1f, gf, z, 0,0,0);
      const int c = nt*16 + l15;
      {
        int f0 = c*20 + lg*4;                          // s = 4*lg + r, 4 consecutive fidx
        int byt = (f0*2) ^ (((f0>>7)&7)<<4);
        uint2v pk;
        pk.x = (unsigned)f2bf(c0[0]) | ((unsigned)f2bf(c0[1])<<16);
        pk.y = (unsigned)f2bf(c0[2]) | ((unsigned)f2bf(c0[3])<<16);
        *(uint2v*)((char*)tbuf + byt) = pk;
      }
      if(lg == 0){
        int f0 = c*20 + 16;                            // s = 16 + r
        int byt = (f0*2) ^ (((f0>>7)&7)<<4);
        uint2v pk;
        pk.x = (unsigned)f2bf(c1[0]) | ((unsigned)f2bf(c1[1])<<16);
        pk.y = (unsigned)f2bf(c1[2]) | ((unsigned)f2bf(c1[3])<<16);
        *(uint2v*)((char*)tbuf + byt) = pk;
      }
    }

    // ---- GEMM2: D[kp][o] = sum_c' T[kp][c'] * W[o][c'] (wf from L1-hot wpack) ----
    f32x4 acc[2][4];
    #pragma unroll
    for(int m2=0;m2<2;m2++)
      #pragma unroll
      for(int n2=0;n2<4;n2++){ f32x4 z={0.f,0.f,0.f,0.f}; acc[m2][n2]=z; }

    const int kp1 = (l15 < 4) ? (16 + l15) : 19;       // clamped; dup rows masked in epilogue
    #pragma unroll
    for(int ks=0; ks<4; ks++){
      int a0b = (l15*256 + ks*64 + lg*16) ^ ((l15&7)<<4);
      int a1b = (kp1*256 + ks*64 + lg*16) ^ ((kp1&7)<<4);
      short8 t0 = *(const short8*)((const char*)tbuf + a0b);
      short8 t1 = *(const short8*)((const char*)tbuf + a1b);
      #pragma unroll
      for(int n2=0; n2<4; n2++){
        short8 wf = *(const short8*)(wpack + (ks*4+n2)*512 + lane*8);
        acc[0][n2] = __builtin_amdgcn_mfma_f32_16x16x32_bf16(t0, wf, acc[0][n2], 0,0,0);
        acc[1][n2] = __builtin_amdgcn_mfma_f32_16x16x32_bf16(t1, wf, acc[1][n2], 0,0,0);
      }
    }

    // ---- prefetch next point into gbuf: its tr-reads are hard-complete (lgkm(0)) ----
    if(pi+1 < PTS_PER_WAVE){ STAGE(pi+1); PERM(pi+1); }

    // ---- epilogue: max over kp, buffer y in LDS, BN partials ----
    #pragma unroll
    for(int n2=0; n2<4; n2++){
      float m0 = fmaxf(fmaxf(acc[0][n2][0], acc[0][n2][1]),
                       fmaxf(acc[0][n2][2], acc[0][n2][3]));
      float m1 = fmaxf(fmaxf(acc[1][n2][0], acc[1][n2][1]),
                       fmaxf(acc[1][n2][2], acc[1][n2][3]));
      float mm = fmaxf(m0, (lg == 0) ? m1 : -3.4e38f);
      mm = fmaxf(mm, __shfl_xor(mm, 16));
      mm = fmaxf(mm, __shfl_xor(mm, 32));
      if(lg == 0) ybuf[pi*64 + n2*16 + l15] = mm;      // conv bias cancels under BN
      bsum[n2] += mm; bsq[n2] += mm*mm;
    }
  }

  // ---- batched out store: lane = channel, 8 consecutive points -> 2x dwordx4 ----
  {
    int o = lane;
    int bb = p0 >> 12, nn0 = p0 & (NPTS-1);
    float* op = out + ((size_t)bb*OUTC + o)*NPTS + nn0;
    float4 v0, v1;
    v0.x = ybuf[0*64+o]; v0.y = ybuf[1*64+o]; v0.z = ybuf[2*64+o]; v0.w = ybuf[3*64+o];
    v1.x = ybuf[4*64+o]; v1.y = ybuf[5*64+o]; v1.z = ybuf[6*64+o]; v1.w = ybuf[7*64+o];
    *(float4*)op     = v0;
    *(float4*)(op+4) = v1;
  }

  // ---- block-level stats reduction -> 2 atomics per channel per block ----
  __syncthreads();
  if(lg == 0){
    #pragma unroll
    for(int n2=0; n2<4; n2++){
      int o = n2*16 + l15;
      red[w*128 + o]      = bsum[n2];
      red[w*128 + 64 + o] = bsq[n2];
    }
  }
  __syncthreads();
  if(w == 0){
    float s = red[lane] + red[128+lane] + red[256+lane] + red[384+lane];
    atomicAdd(&stats[lane], s);
  } else if(w == 1){
    float s = red[64+lane] + red[192+lane] + red[320+lane] + red[448+lane];
    atomicAdd(&stats[64+lane], s);
  }
}

__global__ void k_finalize(const float* __restrict__ stats,
                           const float* __restrict__ gamma,
                           const float* __restrict__ beta,
                           float* __restrict__ ss){
  int o = threadIdx.x;   // 64
  float inv = 1.f/(float)PTOT;
  float mean = stats[o]*inv;
  float var  = stats[64+o]*inv - mean*mean;
  float rstd = rsqrtf(var + 1e-5f);
  float sc = gamma[o]*rstd;
  ss[o] = sc;
  ss[64+o] = beta[o] - mean*sc;
}

__global__ void k_bn(float* __restrict__ out, const float* __restrict__ ss){
  int i = blockIdx.x*256 + threadIdx.x;     // over float4s
  float4 v = ((float4*)out)[i];
  int o = (i >> 10) & 63;
  float sc = ss[o], sh = ss[64+o];
  v.x = v.x*sc + sh; v.y = v.y*sc + sh; v.z = v.z*sc + sh; v.w = v.w*sc + sh;
  ((float4*)out)[i] = v;
}

extern "C" void kernel_launch(void* const* d_in, const int* in_sizes, int n_in,
                              void* d_out, int out_size, void* d_ws, size_t ws_size,
                              hipStream_t stream){
  (void)in_sizes; (void)n_in; (void)ws_size;
  const float* feature    = (const float*)d_in[0];
  const float* permatrix  = (const float*)d_in[1];
  const float* conv_w     = (const float*)d_in[2];
  // d_in[3] = conv_b: cancelled exactly by training-mode BatchNorm
  const float* bn_gamma   = (const float*)d_in[4];
  const float* bn_beta    = (const float*)d_in[5];
  const int*   sp_idx     = (const int*)d_in[6];
  float* out = (float*)d_out;

  unsigned short* flat  = (unsigned short*)d_ws;                         // 8 MB
  float* stats          = (float*)((char*)d_ws + (size_t)8*1024*1024);   // 128 f32
  float* ss             = stats + 128;                                   // 128 f32
  unsigned short* wpack = (unsigned short*)((char*)d_ws + (size_t)8*1024*1024 + 4096); // 16 KB

  hipMemsetAsync(stats, 0, 128*sizeof(float), stream);

  dim3 gT(NPTS/32, FEATS/32, BATCH), bT(32,8);
  k_transpose<<<gT, bT, 0, stream>>>(feature, flat);
  k_wpack<<<dim3(32), dim3(256), 0, stream>>>(conv_w, wpack);

  k_main<<<dim3(PTOT/(WAVES*PTS_PER_WAVE)), dim3(256), 0, stream>>>(
      flat, permatrix, wpack, sp_idx, out, stats);

  k_finalize<<<dim3(1), dim3(64), 0, stream>>>(stats, bn_gamma, bn_beta, ss);

  k_bn<<<dim3(out_size/4/256), dim3(256), 0, stream>>>(out, ss);
}